// Round 4
// baseline (59.868 us; speedup 1.0000x reference)
//
#include <hip/hip_runtime.h>
#include <hip/hip_bf16.h>

#define OUT_CH 64
#define KSZ 7
#define STRIDE 2
#define PAD 3
#define HIDDEN 128
#define MAX_IN 3
#define B_SZ 32
#define H_IN 224
#define W_IN 224
#define H_OUT 112
#define W_OUT 112
#define WPB 147                       // 3*7*7 taps per (b,oc)
#define OUT_DIM (OUT_CH * WPB)        // 9408
#define SEGS 21                       // 3 channels * 7 kh rows
#define SEGP 24                       // padded segment count (6 MFMAs * 4)
#define WQ_PER_B (OUT_CH * SEGP * 8)  // 12288 bf16 per batch row
#define XRW 120                       // u32 per LDS x-row (240 bf16); stride 120%32={0,24,16,8} -> 2-way max
#define NROWD 13                      // ih rows per channel for 4 oh (2*3+7-... span 13)
#define NROWS4 (MAX_IN * NROWD)       // 39 staged rows

typedef __attribute__((ext_vector_type(8))) short short8;
typedef __attribute__((ext_vector_type(4))) float floatx4;

// ---------------- Kernel A: fused weight generator ----------------
// h = relu(mask@W1+b1) for 8 b's in LDS, then wq[b][oc][seg(24)][t(8)] bf16.
// grid(48, 4), block(256): x = o-chunk (256 of 12288 padded slots), y = b-octet.
__global__ void wgen_kernel(const float* __restrict__ mask,
                            const float* __restrict__ W1,
                            const float* __restrict__ b1,
                            const float* __restrict__ W2,
                            const float* __restrict__ b2,
                            __hip_bfloat16* __restrict__ wq) {
    __shared__ float hs[8][HIDDEN];
    const int tid = threadIdx.x;
    const int b0 = blockIdx.y * 8;

    // mlp1 for 8 batch rows: 1024 values, 4 per thread
    for (int i = tid; i < 8 * HIDDEN; i += 256) {
        int q = i >> 7;
        int j = i & (HIDDEN - 1);
        float a = b1[j];
#pragma unroll
        for (int c = 0; c < MAX_IN; ++c)
            a += mask[(b0 + q) * MAX_IN + c] * W1[c * HIDDEN + j];
        hs[q][j] = fmaxf(a, 0.0f);
    }
    __syncthreads();

    const int op = blockIdx.x * 256 + tid;    // 0..12287 padded slot
    const int oc  = op / (SEGP * 8);
    const int rem = op - oc * (SEGP * 8);
    const int seg = rem >> 3;
    const int t   = rem & 7;
    const bool real = (seg < SEGS) && (t < 7);

    float acc[8];
    if (real) {
        int c  = seg / KSZ;
        int kh = seg - c * KSZ;
        int o  = oc * WPB + c * 49 + kh * 7 + t;
        float bias = b2[o];
#pragma unroll
        for (int q = 0; q < 8; ++q) acc[q] = bias;
        const float* w2p = W2 + o;
#pragma unroll 8
        for (int j = 0; j < HIDDEN; ++j) {
            float w = w2p[(size_t)j * OUT_DIM];
#pragma unroll
            for (int q = 0; q < 8; ++q) acc[q] += hs[q][j] * w;
        }
    } else {
#pragma unroll
        for (int q = 0; q < 8; ++q) acc[q] = 0.0f;
    }
#pragma unroll
    for (int q = 0; q < 8; ++q)
        wq[(size_t)(b0 + q) * WQ_PER_B + op] = __float2bfloat16(acc[q]);
}

// ---------------- Kernel B: grouped conv as implicit GEMM (MFMA) ----------------
// grid(28, 32), block(256) = 4 waves. Block: (b, 4 oh rows); wave w -> oh0+w.
// Each wave holds ALL 4 oc-tiles (24 A-frags) so one B-frag feeds 4 MFMAs.
__global__ void __launch_bounds__(256, 2)
conv_kernel(const float* __restrict__ x,
            const __hip_bfloat16* __restrict__ wq,
            float* __restrict__ out) {
    __shared__ unsigned int xs[NROWS4 * XRW];   // 39 rows * 480B = 18.7 KB

    const int oh0 = blockIdx.x * 4;
    const int b   = blockIdx.y;
    const int tid = threadIdx.x;

    // ---- stage x rows: f32 -> packed bf16, zero-padded halo ----
    const float* xb = x + (size_t)b * MAX_IN * H_IN * W_IN;
    for (int i = tid; i < NROWS4 * XRW; i += 256) {
        int row = i / XRW;             // c*13 + d
        int uw  = i - row * XRW;       // 0..119
        int c   = row / NROWD;
        int d   = row - c * NROWD;
        int ih  = oh0 * STRIDE + d - PAD;
        int iw0 = uw * 2 - PAD;
        float f0 = 0.0f, f1 = 0.0f;
        if ((unsigned)ih < (unsigned)H_IN) {
            const float* xr = xb + ((size_t)c * H_IN + ih) * W_IN;
            if ((unsigned)iw0 < (unsigned)W_IN)       f0 = xr[iw0];
            if ((unsigned)(iw0 + 1) < (unsigned)W_IN) f1 = xr[iw0 + 1];
        }
        unsigned int lo = __bfloat16_as_ushort(__float2bfloat16(f0));
        unsigned int hi = __bfloat16_as_ushort(__float2bfloat16(f1));
        xs[i] = lo | (hi << 16);
    }

    const int w  = tid >> 6;            // wave -> local oh
    const int l  = tid & 63;
    const int lr = l & 15;              // A row (oc) / B,D col (pixel)
    const int lg = l >> 4;              // k-group / D row group

    // ---- A-fragments: all 4 oc-tiles x 6 MFMAs, loaded once per block ----
    const unsigned short* wqb = (const unsigned short*)wq + (size_t)b * WQ_PER_B;
    short8 afr[4][6];
#pragma unroll
    for (int q = 0; q < 4; ++q)
#pragma unroll
        for (int mi = 0; mi < 6; ++mi)
            afr[q][mi] = *(const short8*)(wqb + ((size_t)(q * 16 + lr) * SEGP + 4 * mi + lg) * 8);

    __syncthreads();

    // per-lane B row index for each mi (seg = 4mi+lg -> c,kh -> staged row)
    int rowidx[6];
#pragma unroll
    for (int mi = 0; mi < 6; ++mi) {
        int seg = 4 * mi + lg;
        if (seg >= SEGS) seg = 0;       // padded k: A weights are 0 there
        int c  = seg / KSZ;
        int kh = seg - c * KSZ;
        rowidx[mi] = (c * NROWD + 2 * w + kh) * XRW;
    }

    const int oh = oh0 + w;
#pragma unroll
    for (int t = 0; t < 7; ++t) {
        const int ow = t * 16 + lr;
        floatx4 acc[4];
#pragma unroll
        for (int q = 0; q < 4; ++q) acc[q] = (floatx4){0.0f, 0.0f, 0.0f, 0.0f};

#pragma unroll
        for (int mi = 0; mi < 6; ++mi) {
            const unsigned int* xr = xs + rowidx[mi] + ow;
            union { short8 s; unsigned int u[4]; } bu;
            bu.u[0] = xr[0];
            bu.u[1] = xr[1];
            bu.u[2] = xr[2];
            bu.u[3] = xr[3];
#pragma unroll
            for (int q = 0; q < 4; ++q)
                acc[q] = __builtin_amdgcn_mfma_f32_16x16x32_bf16(afr[q][mi], bu.s, acc[q], 0, 0, 0);
        }
#pragma unroll
        for (int q = 0; q < 4; ++q) {
            float* op = out + (((size_t)b * OUT_CH + q * 16 + lg * 4) * H_OUT + oh) * W_OUT + ow;
#pragma unroll
            for (int r = 0; r < 4; ++r)
                op[(size_t)r * H_OUT * W_OUT] = acc[q][r];
        }
    }
}

extern "C" void kernel_launch(void* const* d_in, const int* in_sizes, int n_in,
                              void* d_out, int out_size, void* d_ws, size_t ws_size,
                              hipStream_t stream) {
    const float* x    = (const float*)d_in[0];   // [32,3,224,224]
    const float* mask = (const float*)d_in[1];   // [32,3]
    const float* W1   = (const float*)d_in[2];   // [3,128]
    const float* b1   = (const float*)d_in[3];   // [128]
    const float* W2   = (const float*)d_in[4];   // [128,9408]
    const float* b2   = (const float*)d_in[5];   // [9408]
    float* out = (float*)d_out;

    __hip_bfloat16* wq = (__hip_bfloat16*)d_ws;  // 32*12288*2 = 768 KB

    wgen_kernel<<<dim3(48, 4), dim3(256), 0, stream>>>(mask, W1, b1, W2, b2, wq);
    conv_kernel<<<dim3(28, B_SZ), dim3(256), 0, stream>>>(x, wq, out);
}